// Round 2
// baseline (303.112 us; speedup 1.0000x reference)
//
#include <hip/hip_runtime.h>
#include <hip/hip_bf16.h>

// out[b] = dot(user_factors[users[b]], item_factors[items[b]]), D=64, fp32.
// Simplest-possible correct form: one thread per batch element.
// 16 float4 loads per row (256 B, 16B-aligned), scalar accumulate, one store.
// No shuffles, no LDS, no divergent sub-group ownership.
__global__ __launch_bounds__(256) void mf_dot_kernel(
    const int* __restrict__ users,
    const int* __restrict__ items,
    const float* __restrict__ user_factors,
    const float* __restrict__ item_factors,
    float* __restrict__ out,
    int batch)
{
    int b = blockIdx.x * blockDim.x + threadIdx.x;
    if (b >= batch) return;

    int u = users[b];
    int v = items[b];

    const float4* up = reinterpret_cast<const float4*>(user_factors + (size_t)u * 64);
    const float4* vp = reinterpret_cast<const float4*>(item_factors + (size_t)v * 64);

    float acc = 0.0f;
#pragma unroll
    for (int k = 0; k < 16; ++k) {
        float4 a = up[k];
        float4 c = vp[k];
        acc += a.x * c.x + a.y * c.y + a.z * c.z + a.w * c.w;
    }

    out[b] = acc;
}

extern "C" void kernel_launch(void* const* d_in, const int* in_sizes, int n_in,
                              void* d_out, int out_size, void* d_ws, size_t ws_size,
                              hipStream_t stream)
{
    const int*   users        = (const int*)d_in[0];
    const int*   items        = (const int*)d_in[1];
    const float* user_factors = (const float*)d_in[2];
    const float* item_factors = (const float*)d_in[3];
    float*       out          = (float*)d_out;

    int batch = in_sizes[0];            // 16384
    int block = 256;
    int grid  = (batch + block - 1) / block;   // 64 blocks

    mf_dot_kernel<<<grid, block, 0, stream>>>(users, items, user_factors,
                                              item_factors, out, batch);
}